// Round 7
// baseline (55.883 us; speedup 1.0000x reference)
//
#include <hip/hip_runtime.h>
#include <cmath>

// MXIntGELU via 4096-entry LUT (ex1 in [-8,7] x mantissa in [-128,127]).
// R6: 16 floats/iteration, straight-line within the iteration (4 independent
// float4 loads issued together -- no conditional prefetch for the compiler to
// sink). Lane-pair owns one 32-block (single shfl_xor). 2048 blocks x 256
// threads grid-stride (exactly resident, LUT staged once per block).

typedef float floatx4 __attribute__((ext_vector_type(4)));

__device__ __forceinline__ float pow2i(int k) {
    union { unsigned u; float f; } c;
    c.u = (unsigned)(127 + k) << 23;
    return c.f;
}

__device__ __forceinline__ int block_exp(float amax) {
    // clip(floor(log2(max(amax, 2^-8))), -8, 7) -- exact via ilogb
    int e = ilogbf(fmaxf(amax, 0x1p-8f));
    return max(-8, min(7, e));
}

__global__ __launch_bounds__(256) void build_lut_kernel(float* __restrict__ lut) {
    const int idx = blockIdx.x * 256 + threadIdx.x;   // 0..4095
    const int e = (idx >> 8) - 8;
    const int m = (idx & 255) - 128;
    const float q = (float)m * pow2i(e - 7);
    float r = fmaxf(q, 0.f);                          // relu path
    if (q > -3.f && q < 3.f) {
        const float t = q / 1.41421356237309504880f;
        const float er = (float)erf((double)t);       // correctly-rounded f32 erf
        const float g = q * (er + 1.f) * 0.5f;
        float qg = rintf(g * 32.f);                   // 8b / 5 frac-bit hash quant
        qg = fminf(fmaxf(qg, -128.f), 127.f);
        const float qgelu = qg * 0.03125f;
        const float mg = floorf(qgelu * pow2i(7 - e)); // exponent-aligned floor
        r = mg * pow2i(e - 7);
    }
    lut[idx] = r;
}

__global__ __launch_bounds__(256) void mxint_gelu_lut_kernel(
    const float* __restrict__ in, float* __restrict__ out,
    const float* __restrict__ glut, unsigned n16)
{
    __shared__ float lut[4096];
    {   // fill LDS LUT: 256 threads x 4 x float4 (coalesced, conflict-free)
        const floatx4* g4 = reinterpret_cast<const floatx4*>(glut);
        floatx4* l4 = reinterpret_cast<floatx4*>(lut);
        #pragma unroll
        for (int k = 0; k < 4; ++k)
            l4[threadIdx.x + 256 * k] = g4[threadIdx.x + 256 * k];
    }
    __syncthreads();

    const unsigned stride = gridDim.x * 256u;
    for (unsigned u = blockIdx.x * 256u + threadIdx.x; u < n16; u += stride) {
        // 4 independent loads issued back-to-back, all consumed this iteration
        const floatx4* p = reinterpret_cast<const floatx4*>(in) + 4 * (size_t)u;
        const floatx4 v0 = p[0];
        const floatx4 v1 = p[1];
        const floatx4 v2 = p[2];
        const floatx4 v3 = p[3];

        float x[16] = {v0.x, v0.y, v0.z, v0.w, v1.x, v1.y, v1.z, v1.w,
                       v2.x, v2.y, v2.z, v2.w, v3.x, v3.y, v3.z, v3.w};

        // thread owns 16 consecutive floats; a lane PAIR owns one 32-block
        float amax = 0.f;
        #pragma unroll
        for (int j = 0; j < 16; ++j) amax = fmaxf(amax, fabsf(x[j]));
        amax = fmaxf(amax, __shfl_xor(amax, 1, 64));

        const int ex1 = block_exp(amax);
        const float s1 = pow2i(7 - ex1);          // 128 / 2^ex1
        const int base = (ex1 + 8) * 256 + 128;

        float o[16];
        float oamax = 0.f;
        #pragma unroll
        for (int j = 0; j < 16; ++j) {
            float m = rintf(x[j] * s1);           // round-half-even
            m = fminf(fmaxf(m, -128.f), 127.f);
            const float r = lut[base + (int)m];
            o[j] = r;
            oamax = fmaxf(oamax, fabsf(r));
        }

        oamax = fmaxf(oamax, __shfl_xor(oamax, 1, 64));
        const int ex2 = block_exp(oamax);
        const float s2 = pow2i(7 - ex2);
        const float is2 = pow2i(ex2 - 7);

        floatx4* q = reinterpret_cast<floatx4*>(out) + 4 * (size_t)u;
        #pragma unroll
        for (int k = 0; k < 4; ++k) {
            floatx4 yv;
            float m0 = fminf(fmaxf(rintf(o[4*k+0] * s2), -128.f), 127.f);
            float m1 = fminf(fmaxf(rintf(o[4*k+1] * s2), -128.f), 127.f);
            float m2 = fminf(fmaxf(rintf(o[4*k+2] * s2), -128.f), 127.f);
            float m3 = fminf(fmaxf(rintf(o[4*k+3] * s2), -128.f), 127.f);
            yv.x = m0 * is2; yv.y = m1 * is2; yv.z = m2 * is2; yv.w = m3 * is2;
            q[k] = yv;
        }
    }
}

// Fallback (ws too small or n % 32 != 0): direct computation, identical numerics.
__global__ __launch_bounds__(256) void mxint_gelu_direct_kernel(
    const float* __restrict__ in, float* __restrict__ out, unsigned n4)
{
    unsigned i = blockIdx.x * 256u + threadIdx.x;
    if (i >= n4) return;
    const float4 xv = reinterpret_cast<const float4*>(in)[i];
    float x[4] = {xv.x, xv.y, xv.z, xv.w};
    float amax = fmaxf(fmaxf(fabsf(x[0]), fabsf(x[1])),
                       fmaxf(fabsf(x[2]), fabsf(x[3])));
    amax = fmaxf(amax, __shfl_xor(amax, 1, 64));
    amax = fmaxf(amax, __shfl_xor(amax, 2, 64));
    amax = fmaxf(amax, __shfl_xor(amax, 4, 64));
    const int ex1 = block_exp(amax);
    const float s1 = pow2i(7 - ex1), is1 = pow2i(ex1 - 7);
    float o[4]; float oamax = 0.f;
    #pragma unroll
    for (int j = 0; j < 4; ++j) {
        float m = rintf(x[j] * s1);
        m = fminf(fmaxf(m, -128.f), 127.f);
        const float q = m * is1;
        float r = fmaxf(q, 0.f);
        if (q > -3.f && q < 3.f) {
            const float t = q / 1.41421356237309504880f;
            const float e = (float)erf((double)t);
            const float g = q * (e + 1.f) * 0.5f;
            float qg = rintf(g * 32.f);
            qg = fminf(fmaxf(qg, -128.f), 127.f);
            const float mg = floorf(qg * 0.03125f * s1);
            r = mg * is1;
        }
        o[j] = r; oamax = fmaxf(oamax, fabsf(r));
    }
    oamax = fmaxf(oamax, __shfl_xor(oamax, 1, 64));
    oamax = fmaxf(oamax, __shfl_xor(oamax, 2, 64));
    oamax = fmaxf(oamax, __shfl_xor(oamax, 4, 64));
    const int ex2 = block_exp(oamax);
    const float s2 = pow2i(7 - ex2), is2 = pow2i(ex2 - 7);
    float y[4];
    #pragma unroll
    for (int j = 0; j < 4; ++j) {
        float m = rintf(o[j] * s2);
        m = fminf(fmaxf(m, -128.f), 127.f);
        y[j] = m * is2;
    }
    reinterpret_cast<float4*>(out)[i] =
        make_float4(y[0], y[1], y[2], y[3]);
}

extern "C" void kernel_launch(void* const* d_in, const int* in_sizes, int n_in,
                              void* d_out, int out_size, void* d_ws, size_t ws_size,
                              hipStream_t stream) {
    const float* x = (const float*)d_in[0];
    float* y = (float*)d_out;
    const unsigned n = (unsigned)in_sizes[0];   // 33,554,432

    if (ws_size >= 4096 * sizeof(float) && (n % 32u) == 0u) {
        float* lut = (float*)d_ws;
        build_lut_kernel<<<16, 256, 0, stream>>>(lut);
        const unsigned n16 = n / 16;
        unsigned blocks = 2048;                 // 8 blocks/CU, grid-stride
        if (blocks * 256u > n16) blocks = (n16 + 255u) / 256u;
        mxint_gelu_lut_kernel<<<blocks, 256, 0, stream>>>(x, y, lut, n16);
    } else {
        const unsigned n4 = n / 4;
        mxint_gelu_direct_kernel<<<(n4 + 255u) / 256u, 256, 0, stream>>>(x, y, n4);
    }
}

// Round 8
// 51.534 us; speedup vs baseline: 1.0844x; 1.0844x over previous
//
#include <hip/hip_runtime.h>
#include <cmath>

// MXIntGELU via 4096-entry LUT (ex1 in [-8,7] x mantissa in [-128,127]).
// R7: dual independent chains per thread -- chunk u (first half) and chunk
// u+half (second half), each 8 floats with its own amax/shfl/LUT/store chain.
// The two chains share no data, so the scheduler can interleave them to hide
// shuffle+LDS latency without any loop-carried prefetch (which it keeps
// deleting). Best-known base config otherwise: 2048 blocks x 256 threads.

typedef float floatx4 __attribute__((ext_vector_type(4)));

__device__ __forceinline__ float pow2i(int k) {
    union { unsigned u; float f; } c;
    c.u = (unsigned)(127 + k) << 23;
    return c.f;
}

__device__ __forceinline__ int block_exp(float amax) {
    // clip(floor(log2(max(amax, 2^-8))), -8, 7) -- exact via ilogb
    int e = ilogbf(fmaxf(amax, 0x1p-8f));
    return max(-8, min(7, e));
}

__global__ __launch_bounds__(256) void build_lut_kernel(float* __restrict__ lut) {
    const int idx = blockIdx.x * 256 + threadIdx.x;   // 0..4095
    const int e = (idx >> 8) - 8;
    const int m = (idx & 255) - 128;
    const float q = (float)m * pow2i(e - 7);
    float r = fmaxf(q, 0.f);                          // relu path
    if (q > -3.f && q < 3.f) {
        const float t = q / 1.41421356237309504880f;
        const float er = (float)erf((double)t);       // correctly-rounded f32 erf
        const float g = q * (er + 1.f) * 0.5f;
        float qg = rintf(g * 32.f);                   // 8b / 5 frac-bit hash quant
        qg = fminf(fmaxf(qg, -128.f), 127.f);
        const float qgelu = qg * 0.03125f;
        const float mg = floorf(qgelu * pow2i(7 - e)); // exponent-aligned floor
        r = mg * pow2i(e - 7);
    }
    lut[idx] = r;
}

__global__ __launch_bounds__(256) void mxint_gelu_lut_kernel(
    const float* __restrict__ in, float* __restrict__ out,
    const float* __restrict__ glut, unsigned half8)
{
    __shared__ float lut[4096];
    {   // fill LDS LUT: 256 threads x 4 x float4 (coalesced, conflict-free)
        const floatx4* g4 = reinterpret_cast<const floatx4*>(glut);
        floatx4* l4 = reinterpret_cast<floatx4*>(lut);
        #pragma unroll
        for (int k = 0; k < 4; ++k)
            l4[threadIdx.x + 256 * k] = g4[threadIdx.x + 256 * k];
    }
    __syncthreads();

    const unsigned stride = gridDim.x * 256u;
    for (unsigned u = blockIdx.x * 256u + threadIdx.x; u < half8; u += stride) {
        // ---- issue all 4 independent loads (2 per chain) ----
        const floatx4* pA = reinterpret_cast<const floatx4*>(in) + 2 * (size_t)u;
        const floatx4* pB = reinterpret_cast<const floatx4*>(in)
                          + 2 * (size_t)(u + half8);
        const floatx4 a0 = pA[0], a1 = pA[1];
        const floatx4 b0 = pB[0], b1 = pB[1];

        float xa[8] = {a0.x, a0.y, a0.z, a0.w, a1.x, a1.y, a1.z, a1.w};
        float xb[8] = {b0.x, b0.y, b0.z, b0.w, b1.x, b1.y, b1.z, b1.w};

        // ---- independent amax trees (lane QUAD owns a 32-block) ----
        float amaxA = 0.f, amaxB = 0.f;
        #pragma unroll
        for (int j = 0; j < 8; ++j) {
            amaxA = fmaxf(amaxA, fabsf(xa[j]));
            amaxB = fmaxf(amaxB, fabsf(xb[j]));
        }
        amaxA = fmaxf(amaxA, __shfl_xor(amaxA, 1, 64));
        amaxB = fmaxf(amaxB, __shfl_xor(amaxB, 1, 64));
        amaxA = fmaxf(amaxA, __shfl_xor(amaxA, 2, 64));
        amaxB = fmaxf(amaxB, __shfl_xor(amaxB, 2, 64));

        const int exA = block_exp(amaxA);
        const int exB = block_exp(amaxB);
        const float sA = pow2i(7 - exA);
        const float sB = pow2i(7 - exB);
        const int baseA = (exA + 8) * 256 + 128;
        const int baseB = (exB + 8) * 256 + 128;

        // ---- interleaved LUT gathers ----
        float oa[8], ob[8];
        float oamaxA = 0.f, oamaxB = 0.f;
        #pragma unroll
        for (int j = 0; j < 8; ++j) {
            float ma = rintf(xa[j] * sA);
            float mb = rintf(xb[j] * sB);
            ma = fminf(fmaxf(ma, -128.f), 127.f);
            mb = fminf(fmaxf(mb, -128.f), 127.f);
            const float ra = lut[baseA + (int)ma];
            const float rb = lut[baseB + (int)mb];
            oa[j] = ra; ob[j] = rb;
            oamaxA = fmaxf(oamaxA, fabsf(ra));
            oamaxB = fmaxf(oamaxB, fabsf(rb));
        }

        oamaxA = fmaxf(oamaxA, __shfl_xor(oamaxA, 1, 64));
        oamaxB = fmaxf(oamaxB, __shfl_xor(oamaxB, 1, 64));
        oamaxA = fmaxf(oamaxA, __shfl_xor(oamaxA, 2, 64));
        oamaxB = fmaxf(oamaxB, __shfl_xor(oamaxB, 2, 64));

        const int e2A = block_exp(oamaxA);
        const int e2B = block_exp(oamaxB);
        const float s2A = pow2i(7 - e2A), is2A = pow2i(e2A - 7);
        const float s2B = pow2i(7 - e2B), is2B = pow2i(e2B - 7);

        floatx4* qA = reinterpret_cast<floatx4*>(out) + 2 * (size_t)u;
        floatx4* qB = reinterpret_cast<floatx4*>(out) + 2 * (size_t)(u + half8);
        #pragma unroll
        for (int k = 0; k < 2; ++k) {
            floatx4 ya, yb;
            float a0_ = fminf(fmaxf(rintf(oa[4*k+0] * s2A), -128.f), 127.f);
            float a1_ = fminf(fmaxf(rintf(oa[4*k+1] * s2A), -128.f), 127.f);
            float a2_ = fminf(fmaxf(rintf(oa[4*k+2] * s2A), -128.f), 127.f);
            float a3_ = fminf(fmaxf(rintf(oa[4*k+3] * s2A), -128.f), 127.f);
            float b0_ = fminf(fmaxf(rintf(ob[4*k+0] * s2B), -128.f), 127.f);
            float b1_ = fminf(fmaxf(rintf(ob[4*k+1] * s2B), -128.f), 127.f);
            float b2_ = fminf(fmaxf(rintf(ob[4*k+2] * s2B), -128.f), 127.f);
            float b3_ = fminf(fmaxf(rintf(ob[4*k+3] * s2B), -128.f), 127.f);
            ya.x = a0_ * is2A; ya.y = a1_ * is2A; ya.z = a2_ * is2A; ya.w = a3_ * is2A;
            yb.x = b0_ * is2B; yb.y = b1_ * is2B; yb.z = b2_ * is2B; yb.w = b3_ * is2B;
            qA[k] = ya;
            qB[k] = yb;
        }
    }
}

// Fallback (ws too small or n % 64 != 0): direct computation, identical numerics.
__global__ __launch_bounds__(256) void mxint_gelu_direct_kernel(
    const float* __restrict__ in, float* __restrict__ out, unsigned n4)
{
    unsigned i = blockIdx.x * 256u + threadIdx.x;
    if (i >= n4) return;
    const float4 xv = reinterpret_cast<const float4*>(in)[i];
    float x[4] = {xv.x, xv.y, xv.z, xv.w};
    float amax = fmaxf(fmaxf(fabsf(x[0]), fabsf(x[1])),
                       fmaxf(fabsf(x[2]), fabsf(x[3])));
    amax = fmaxf(amax, __shfl_xor(amax, 1, 64));
    amax = fmaxf(amax, __shfl_xor(amax, 2, 64));
    amax = fmaxf(amax, __shfl_xor(amax, 4, 64));
    const int ex1 = block_exp(amax);
    const float s1 = pow2i(7 - ex1), is1 = pow2i(ex1 - 7);
    float o[4]; float oamax = 0.f;
    #pragma unroll
    for (int j = 0; j < 4; ++j) {
        float m = rintf(x[j] * s1);
        m = fminf(fmaxf(m, -128.f), 127.f);
        const float q = m * is1;
        float r = fmaxf(q, 0.f);
        if (q > -3.f && q < 3.f) {
            const float t = q / 1.41421356237309504880f;
            const float e = (float)erf((double)t);
            const float g = q * (e + 1.f) * 0.5f;
            float qg = rintf(g * 32.f);
            qg = fminf(fmaxf(qg, -128.f), 127.f);
            const float mg = floorf(qg * 0.03125f * s1);
            r = mg * is1;
        }
        o[j] = r; oamax = fmaxf(oamax, fabsf(r));
    }
    oamax = fmaxf(oamax, __shfl_xor(oamax, 1, 64));
    oamax = fmaxf(oamax, __shfl_xor(oamax, 2, 64));
    oamax = fmaxf(oamax, __shfl_xor(oamax, 4, 64));
    const int ex2 = block_exp(oamax);
    const float s2 = pow2i(7 - ex2), is2 = pow2i(ex2 - 7);
    float y[4];
    #pragma unroll
    for (int j = 0; j < 4; ++j) {
        float m = rintf(o[j] * s2);
        m = fminf(fmaxf(m, -128.f), 127.f);
        y[j] = m * is2;
    }
    reinterpret_cast<float4*>(out)[i] =
        make_float4(y[0], y[1], y[2], y[3]);
}

extern "C" void kernel_launch(void* const* d_in, const int* in_sizes, int n_in,
                              void* d_out, int out_size, void* d_ws, size_t ws_size,
                              hipStream_t stream) {
    const float* x = (const float*)d_in[0];
    float* y = (float*)d_out;
    const unsigned n = (unsigned)in_sizes[0];   // 33,554,432

    if (ws_size >= 4096 * sizeof(float) && (n % 64u) == 0u) {
        float* lut = (float*)d_ws;
        build_lut_kernel<<<16, 256, 0, stream>>>(lut);
        const unsigned half8 = n / 16;          // chunks-of-8 per half
        unsigned blocks = 2048;                 // 8 blocks/CU, grid-stride
        if (blocks * 256u > half8) blocks = (half8 + 255u) / 256u;
        mxint_gelu_lut_kernel<<<blocks, 256, 0, stream>>>(x, y, lut, half8);
    } else {
        const unsigned n4 = n / 4;
        mxint_gelu_direct_kernel<<<(n4 + 255u) / 256u, 256, 0, stream>>>(x, y, n4);
    }
}

// Round 9
// 50.664 us; speedup vs baseline: 1.1030x; 1.0172x over previous
//
#include <hip/hip_runtime.h>
#include <cmath>

// MXIntGELU via 4096-entry LUT (ex1 in [-8,7] x mantissa in [-128,127]).
// R8: coalescing-exact layout. A wave owns 512 contiguous floats (128 float4).
// Register k in {0,1} loads in4[region*128 + k*64 + lane] -> lane-stride 16 B,
// every load/store instruction covers whole 64B lines (1x L2 transactions;
// the 8/16-float-per-thread contiguous variants had 2x/4x inflation, matching
// their measured regressions). Lane-group of 8 holds 32-block g of page k in
// register k -> shfl_xor masks 1,2,4 stay in-group; two independent chains.

typedef float floatx4 __attribute__((ext_vector_type(4)));

__device__ __forceinline__ float pow2i(int k) {
    union { unsigned u; float f; } c;
    c.u = (unsigned)(127 + k) << 23;
    return c.f;
}

__device__ __forceinline__ int block_exp(float amax) {
    // clip(floor(log2(max(amax, 2^-8))), -8, 7) -- exact via ilogb
    int e = ilogbf(fmaxf(amax, 0x1p-8f));
    return max(-8, min(7, e));
}

__global__ __launch_bounds__(256) void build_lut_kernel(float* __restrict__ lut) {
    const int idx = blockIdx.x * 256 + threadIdx.x;   // 0..4095
    const int e = (idx >> 8) - 8;
    const int m = (idx & 255) - 128;
    const float q = (float)m * pow2i(e - 7);
    float r = fmaxf(q, 0.f);                          // relu path
    if (q > -3.f && q < 3.f) {
        const float t = q / 1.41421356237309504880f;
        const float er = (float)erf((double)t);       // correctly-rounded f32 erf
        const float g = q * (er + 1.f) * 0.5f;
        float qg = rintf(g * 32.f);                   // 8b / 5 frac-bit hash quant
        qg = fminf(fmaxf(qg, -128.f), 127.f);
        const float qgelu = qg * 0.03125f;
        const float mg = floorf(qgelu * pow2i(7 - e)); // exponent-aligned floor
        r = mg * pow2i(e - 7);
    }
    lut[idx] = r;
}

__device__ __forceinline__ void process_page(
    const float* __restrict__ lut, const floatx4 v, floatx4& y)
{
    float x[4] = {v.x, v.y, v.z, v.w};

    // 8-lane group reduction: group g = lanes 8g..8g+7 holds one 32-block
    float amax = fmaxf(fmaxf(fabsf(x[0]), fabsf(x[1])),
                       fmaxf(fabsf(x[2]), fabsf(x[3])));
    amax = fmaxf(amax, __shfl_xor(amax, 1, 64));
    amax = fmaxf(amax, __shfl_xor(amax, 2, 64));
    amax = fmaxf(amax, __shfl_xor(amax, 4, 64));

    const int ex1 = block_exp(amax);
    const float s1 = pow2i(7 - ex1);          // 128 / 2^ex1
    const int base = (ex1 + 8) * 256 + 128;

    float o[4];
    float oamax = 0.f;
    #pragma unroll
    for (int j = 0; j < 4; ++j) {
        float m = rintf(x[j] * s1);           // round-half-even
        m = fminf(fmaxf(m, -128.f), 127.f);
        const float r = lut[base + (int)m];
        o[j] = r;
        oamax = fmaxf(oamax, fabsf(r));
    }

    oamax = fmaxf(oamax, __shfl_xor(oamax, 1, 64));
    oamax = fmaxf(oamax, __shfl_xor(oamax, 2, 64));
    oamax = fmaxf(oamax, __shfl_xor(oamax, 4, 64));
    const int ex2 = block_exp(oamax);
    const float s2 = pow2i(7 - ex2);
    const float is2 = pow2i(ex2 - 7);

    #pragma unroll
    for (int j = 0; j < 4; ++j) {
        float m = rintf(o[j] * s2);
        m = fminf(fmaxf(m, -128.f), 127.f);
        o[j] = m * is2;
    }
    y.x = o[0]; y.y = o[1]; y.z = o[2]; y.w = o[3];
}

__global__ __launch_bounds__(256) void mxint_gelu_lut_kernel(
    const float* __restrict__ in, float* __restrict__ out,
    const float* __restrict__ glut, unsigned nregions)
{
    __shared__ float lut[4096];
    {   // fill LDS LUT: 256 threads x 4 x float4 (coalesced, conflict-free)
        const floatx4* g4 = reinterpret_cast<const floatx4*>(glut);
        floatx4* l4 = reinterpret_cast<floatx4*>(lut);
        #pragma unroll
        for (int k = 0; k < 4; ++k)
            l4[threadIdx.x + 256 * k] = g4[threadIdx.x + 256 * k];
    }
    __syncthreads();

    const unsigned lane = threadIdx.x & 63u;
    const unsigned wid = (blockIdx.x * 256u + threadIdx.x) >> 6;
    const unsigned nwaves = gridDim.x * 4u;   // 256 threads = 4 waves/block
    const floatx4* in4 = reinterpret_cast<const floatx4*>(in);
    floatx4* out4 = reinterpret_cast<floatx4*>(out);

    for (unsigned r = wid; r < nregions; r += nwaves) {
        const size_t b = (size_t)r * 128 + lane;
        // two perfectly-coalesced loads (lane-stride 16 B), independent chains
        const floatx4 v0 = in4[b];
        const floatx4 v1 = in4[b + 64];

        floatx4 y0, y1;
        process_page(lut, v0, y0);
        process_page(lut, v1, y1);

        out4[b] = y0;
        out4[b + 64] = y1;
    }
}

// Fallback (ws too small or n % 512 != 0): direct computation, identical numerics.
__global__ __launch_bounds__(256) void mxint_gelu_direct_kernel(
    const float* __restrict__ in, float* __restrict__ out, unsigned n4)
{
    unsigned i = blockIdx.x * 256u + threadIdx.x;
    if (i >= n4) return;
    const float4 xv = reinterpret_cast<const float4*>(in)[i];
    float x[4] = {xv.x, xv.y, xv.z, xv.w};
    float amax = fmaxf(fmaxf(fabsf(x[0]), fabsf(x[1])),
                       fmaxf(fabsf(x[2]), fabsf(x[3])));
    amax = fmaxf(amax, __shfl_xor(amax, 1, 64));
    amax = fmaxf(amax, __shfl_xor(amax, 2, 64));
    amax = fmaxf(amax, __shfl_xor(amax, 4, 64));
    const int ex1 = block_exp(amax);
    const float s1 = pow2i(7 - ex1), is1 = pow2i(ex1 - 7);
    float o[4]; float oamax = 0.f;
    #pragma unroll
    for (int j = 0; j < 4; ++j) {
        float m = rintf(x[j] * s1);
        m = fminf(fmaxf(m, -128.f), 127.f);
        const float q = m * is1;
        float r = fmaxf(q, 0.f);
        if (q > -3.f && q < 3.f) {
            const float t = q / 1.41421356237309504880f;
            const float e = (float)erf((double)t);
            const float g = q * (e + 1.f) * 0.5f;
            float qg = rintf(g * 32.f);
            qg = fminf(fmaxf(qg, -128.f), 127.f);
            const float mg = floorf(qg * 0.03125f * s1);
            r = mg * is1;
        }
        o[j] = r; oamax = fmaxf(oamax, fabsf(r));
    }
    oamax = fmaxf(oamax, __shfl_xor(oamax, 1, 64));
    oamax = fmaxf(oamax, __shfl_xor(oamax, 2, 64));
    oamax = fmaxf(oamax, __shfl_xor(oamax, 4, 64));
    const int ex2 = block_exp(oamax);
    const float s2 = pow2i(7 - ex2), is2 = pow2i(ex2 - 7);
    float y[4];
    #pragma unroll
    for (int j = 0; j < 4; ++j) {
        float m = rintf(o[j] * s2);
        m = fminf(fmaxf(m, -128.f), 127.f);
        y[j] = m * is2;
    }
    reinterpret_cast<float4*>(out)[i] =
        make_float4(y[0], y[1], y[2], y[3]);
}

extern "C" void kernel_launch(void* const* d_in, const int* in_sizes, int n_in,
                              void* d_out, int out_size, void* d_ws, size_t ws_size,
                              hipStream_t stream) {
    const float* x = (const float*)d_in[0];
    float* y = (float*)d_out;
    const unsigned n = (unsigned)in_sizes[0];   // 33,554,432

    if (ws_size >= 4096 * sizeof(float) && (n % 512u) == 0u) {
        float* lut = (float*)d_ws;
        build_lut_kernel<<<16, 256, 0, stream>>>(lut);
        const unsigned nregions = n / 512;      // 512 floats per wave-region
        unsigned blocks = 2048;                 // 8 blocks/CU, grid-stride
        if (blocks * 4u > nregions) blocks = (nregions + 3u) / 4u;
        mxint_gelu_lut_kernel<<<blocks, 256, 0, stream>>>(x, y, lut, nregions);
    } else {
        const unsigned n4 = n / 4;
        mxint_gelu_direct_kernel<<<(n4 + 255u) / 256u, 256, 0, stream>>>(x, y, n4);
    }
}

// Round 10
// 50.511 us; speedup vs baseline: 1.1064x; 1.0030x over previous
//
#include <hip/hip_runtime.h>
#include <cmath>

// MXIntGELU via 4096-entry LUT (ex1 in [-8,7] x mantissa in [-128,127]).
// R9: R8's coalescing-exact layout (wave owns contiguous region; register k
// loads in4[base + k*64 + lane] -> lane-stride 16 B, whole 64B lines) with
// FOUR independent pages per wave-iteration. Each page = its own 32-block set
// with its own 8-lane-group reduction -> 4 fully independent chains per
// iteration body, nothing the compiler can sink (all loads consumed here).

typedef float floatx4 __attribute__((ext_vector_type(4)));

__device__ __forceinline__ float pow2i(int k) {
    union { unsigned u; float f; } c;
    c.u = (unsigned)(127 + k) << 23;
    return c.f;
}

__device__ __forceinline__ int block_exp(float amax) {
    // clip(floor(log2(max(amax, 2^-8))), -8, 7) -- exact via ilogb
    int e = ilogbf(fmaxf(amax, 0x1p-8f));
    return max(-8, min(7, e));
}

__global__ __launch_bounds__(256) void build_lut_kernel(float* __restrict__ lut) {
    const int idx = blockIdx.x * 256 + threadIdx.x;   // 0..4095
    const int e = (idx >> 8) - 8;
    const int m = (idx & 255) - 128;
    const float q = (float)m * pow2i(e - 7);
    float r = fmaxf(q, 0.f);                          // relu path
    if (q > -3.f && q < 3.f) {
        const float t = q / 1.41421356237309504880f;
        const float er = (float)erf((double)t);       // correctly-rounded f32 erf
        const float g = q * (er + 1.f) * 0.5f;
        float qg = rintf(g * 32.f);                   // 8b / 5 frac-bit hash quant
        qg = fminf(fmaxf(qg, -128.f), 127.f);
        const float qgelu = qg * 0.03125f;
        const float mg = floorf(qgelu * pow2i(7 - e)); // exponent-aligned floor
        r = mg * pow2i(e - 7);
    }
    lut[idx] = r;
}

__device__ __forceinline__ void process_page(
    const float* __restrict__ lut, const floatx4 v, floatx4& y)
{
    float x[4] = {v.x, v.y, v.z, v.w};

    // 8-lane group reduction: group g = lanes 8g..8g+7 holds one 32-block
    float amax = fmaxf(fmaxf(fabsf(x[0]), fabsf(x[1])),
                       fmaxf(fabsf(x[2]), fabsf(x[3])));
    amax = fmaxf(amax, __shfl_xor(amax, 1, 64));
    amax = fmaxf(amax, __shfl_xor(amax, 2, 64));
    amax = fmaxf(amax, __shfl_xor(amax, 4, 64));

    const int ex1 = block_exp(amax);
    const float s1 = pow2i(7 - ex1);          // 128 / 2^ex1
    const int base = (ex1 + 8) * 256 + 128;

    float o[4];
    float oamax = 0.f;
    #pragma unroll
    for (int j = 0; j < 4; ++j) {
        float m = rintf(x[j] * s1);           // round-half-even
        m = fminf(fmaxf(m, -128.f), 127.f);
        const float r = lut[base + (int)m];
        o[j] = r;
        oamax = fmaxf(oamax, fabsf(r));
    }

    oamax = fmaxf(oamax, __shfl_xor(oamax, 1, 64));
    oamax = fmaxf(oamax, __shfl_xor(oamax, 2, 64));
    oamax = fmaxf(oamax, __shfl_xor(oamax, 4, 64));
    const int ex2 = block_exp(oamax);
    const float s2 = pow2i(7 - ex2);
    const float is2 = pow2i(ex2 - 7);

    #pragma unroll
    for (int j = 0; j < 4; ++j) {
        float m = rintf(o[j] * s2);
        m = fminf(fmaxf(m, -128.f), 127.f);
        o[j] = m * is2;
    }
    y.x = o[0]; y.y = o[1]; y.z = o[2]; y.w = o[3];
}

__global__ __launch_bounds__(256) void mxint_gelu_lut_kernel(
    const float* __restrict__ in, float* __restrict__ out,
    const float* __restrict__ glut, unsigned nregions)
{
    __shared__ float lut[4096];
    {   // fill LDS LUT: 256 threads x 4 x float4 (coalesced, conflict-free)
        const floatx4* g4 = reinterpret_cast<const floatx4*>(glut);
        floatx4* l4 = reinterpret_cast<floatx4*>(lut);
        #pragma unroll
        for (int k = 0; k < 4; ++k)
            l4[threadIdx.x + 256 * k] = g4[threadIdx.x + 256 * k];
    }
    __syncthreads();

    const unsigned lane = threadIdx.x & 63u;
    const unsigned wid = (blockIdx.x * 256u + threadIdx.x) >> 6;
    const unsigned nwaves = gridDim.x * 4u;   // 256 threads = 4 waves/block
    const floatx4* in4 = reinterpret_cast<const floatx4*>(in);
    floatx4* out4 = reinterpret_cast<floatx4*>(out);

    for (unsigned r = wid; r < nregions; r += nwaves) {
        const size_t b = (size_t)r * 256 + lane;   // region = 1024 floats
        // four perfectly-coalesced loads; four independent chains
        const floatx4 v0 = in4[b];
        const floatx4 v1 = in4[b + 64];
        const floatx4 v2 = in4[b + 128];
        const floatx4 v3 = in4[b + 192];

        floatx4 y0, y1, y2, y3;
        process_page(lut, v0, y0);
        process_page(lut, v1, y1);
        process_page(lut, v2, y2);
        process_page(lut, v3, y3);

        out4[b] = y0;
        out4[b + 64] = y1;
        out4[b + 128] = y2;
        out4[b + 192] = y3;
    }
}

// Fallback (ws too small or n % 1024 != 0): direct computation, identical numerics.
__global__ __launch_bounds__(256) void mxint_gelu_direct_kernel(
    const float* __restrict__ in, float* __restrict__ out, unsigned n4)
{
    unsigned i = blockIdx.x * 256u + threadIdx.x;
    if (i >= n4) return;
    const float4 xv = reinterpret_cast<const float4*>(in)[i];
    float x[4] = {xv.x, xv.y, xv.z, xv.w};
    float amax = fmaxf(fmaxf(fabsf(x[0]), fabsf(x[1])),
                       fmaxf(fabsf(x[2]), fabsf(x[3])));
    amax = fmaxf(amax, __shfl_xor(amax, 1, 64));
    amax = fmaxf(amax, __shfl_xor(amax, 2, 64));
    amax = fmaxf(amax, __shfl_xor(amax, 4, 64));
    const int ex1 = block_exp(amax);
    const float s1 = pow2i(7 - ex1), is1 = pow2i(ex1 - 7);
    float o[4]; float oamax = 0.f;
    #pragma unroll
    for (int j = 0; j < 4; ++j) {
        float m = rintf(x[j] * s1);
        m = fminf(fmaxf(m, -128.f), 127.f);
        const float q = m * is1;
        float r = fmaxf(q, 0.f);
        if (q > -3.f && q < 3.f) {
            const float t = q / 1.41421356237309504880f;
            const float e = (float)erf((double)t);
            const float g = q * (e + 1.f) * 0.5f;
            float qg = rintf(g * 32.f);
            qg = fminf(fmaxf(qg, -128.f), 127.f);
            const float mg = floorf(qg * 0.03125f * s1);
            r = mg * is1;
        }
        o[j] = r; oamax = fmaxf(oamax, fabsf(r));
    }
    oamax = fmaxf(oamax, __shfl_xor(oamax, 1, 64));
    oamax = fmaxf(oamax, __shfl_xor(oamax, 2, 64));
    oamax = fmaxf(oamax, __shfl_xor(oamax, 4, 64));
    const int ex2 = block_exp(oamax);
    const float s2 = pow2i(7 - ex2), is2 = pow2i(ex2 - 7);
    float y[4];
    #pragma unroll
    for (int j = 0; j < 4; ++j) {
        float m = rintf(o[j] * s2);
        m = fminf(fmaxf(m, -128.f), 127.f);
        y[j] = m * is2;
    }
    reinterpret_cast<float4*>(out)[i] =
        make_float4(y[0], y[1], y[2], y[3]);
}

extern "C" void kernel_launch(void* const* d_in, const int* in_sizes, int n_in,
                              void* d_out, int out_size, void* d_ws, size_t ws_size,
                              hipStream_t stream) {
    const float* x = (const float*)d_in[0];
    float* y = (float*)d_out;
    const unsigned n = (unsigned)in_sizes[0];   // 33,554,432

    if (ws_size >= 4096 * sizeof(float) && (n % 1024u) == 0u) {
        float* lut = (float*)d_ws;
        build_lut_kernel<<<16, 256, 0, stream>>>(lut);
        const unsigned nregions = n / 1024;     // 1024 floats per wave-region
        unsigned blocks = 2048;                 // 8 blocks/CU, grid-stride
        if (blocks * 4u > nregions) blocks = (nregions + 3u) / 4u;
        mxint_gelu_lut_kernel<<<blocks, 256, 0, stream>>>(x, y, lut, nregions);
    } else {
        const unsigned n4 = n / 4;
        mxint_gelu_direct_kernel<<<(n4 + 255u) / 256u, 256, 0, stream>>>(x, y, n4);
    }
}